// Round 7
// baseline (734.507 us; speedup 1.0000x reference)
//
#include <hip/hip_runtime.h>
#include <hip/hip_bf16.h>
#include <math.h>

#define B_ 64
#define T_ 4096
#define C_ 256
#define H_ 4
#define HD_ 64
#define EPS_ 1e-5f

#define TILE_ 64
#define NBLK_ 64    // T_/TILE_ tiles per batch
#define NT_ 4       // tiles per persistent k1 block
#define GRID1_ 1024 // (B_*NBLK_)/NT_  -> exactly 4 blocks/CU, all resident

typedef __attribute__((ext_vector_type(4))) float floatx4;
typedef __attribute__((ext_vector_type(8))) short short8;   // 8 bf16 = 4 VGPRs (MFMA A/B frag)

#if __has_builtin(__builtin_amdgcn_cvt_pk_bf16_f32)
typedef __attribute__((ext_vector_type(2))) __bf16 bf16x2_t;
__device__ __forceinline__ unsigned int pack_bf16x2(float a, float b) {
    bf16x2_t v = __builtin_amdgcn_cvt_pk_bf16_f32(a, b);
    return __builtin_bit_cast(unsigned int, v);
}
#else
__device__ __forceinline__ unsigned int pack_bf16x2(float a, float b) {
    unsigned int ua = __builtin_bit_cast(unsigned int, a);
    unsigned int ub = __builtin_bit_cast(unsigned int, b);
    ua = (ua + 0x7fffu + ((ua >> 16) & 1u)) >> 16;   // RNE
    ub = (ub + 0x7fffu + ((ub >> 16) & 1u)) >> 16;
    return ua | (ub << 16);
}
#endif

// tanh(x) = 1 - 2/(e^{2x}+1) = 1 - 2*rcp(exp2(x*2log2e)+1); ~5 ops, err ~1e-7.
__device__ __forceinline__ float fast_tanh(float v) {
    float t = v * 2.8853900817779268f;          // 2*log2(e)
#if __has_builtin(__builtin_amdgcn_exp2f)
    float e2 = __builtin_amdgcn_exp2f(t);
#else
    float e2 = exp2f(t);
#endif
#if __has_builtin(__builtin_amdgcn_rcpf)
    return fmaf(-2.0f, __builtin_amdgcn_rcpf(e2 + 1.0f), 1.0f);
#else
    return 1.0f - 2.0f / (e2 + 1.0f);
#endif
}

// ---------------- K0: W1 (H,C,HD) fp32 -> fragment-major bf16 B-operand ----------------
// w1f[((h*8 + ks)*4 + nb)*64 + lane] = uint4 holding 8 bf16:
//   B[nb*16 + nl][ks*32 + q*8 + j], j=0..7   (nl = lane&15, q = lane>>4)
__global__ void k0_w1frag(const float* __restrict__ W1, uint4* __restrict__ w1f) {
    int h  = blockIdx.x >> 3;       // grid 32 = H*8
    int ks = blockIdx.x & 7;
    int nb = threadIdx.x >> 6;      // 4 waves = 4 n-tiles
    int l  = threadIdx.x & 63;
    int nl = l & 15, q = l >> 4;
    int d  = nb * 16 + nl;
    const float* src = W1 + ((long)h * C_ + ks * 32 + q * 8) * HD_ + d;
    float v[8];
    #pragma unroll
    for (int j = 0; j < 8; ++j) v[j] = src[j * HD_];
    uint4 ua;
    ua.x = pack_bf16x2(v[0], v[1]); ua.y = pack_bf16x2(v[2], v[3]);
    ua.z = pack_bf16x2(v[4], v[5]); ua.w = pack_bf16x2(v[6], v[7]);
    w1f[((long)blockIdx.x * 4 + nb) * 64 + l] = ua;
}

// ---------------- K1: persistent 4-tile pipeline ----------------
// grid 1024, block 256 = 4 waves, wave w = head w. Each block owns tiles
// g*4 .. g*4+3 (64 rows each). Tile i+1's global loads are ISSUED during
// tile i's epilogue/phase-3 (T14 async-STAGE): only tile 0's stage latency
// is exposed. 2 barriers per tile, same verified R2 data layouts throughout.
#define ASTRIDE 264   // bf16 elements per row (256 + 8 pad)
__global__ __launch_bounds__(256, 4)
void k1_fused(const float* __restrict__ x, const uint4* __restrict__ w1f,
              const float* __restrict__ b1, const float* __restrict__ w2,
              float* __restrict__ rawscore, float* __restrict__ ctxp,
              float* __restrict__ mS) {
    __shared__ __align__(16) unsigned short shA[TILE_ * ASTRIDE];  // 33 KiB
    __shared__ float sS[4 * TILE_];
    __shared__ __align__(16) float sP4[TILE_ * 4];

    const int tid  = threadIdx.x;
    const int lane = tid & 63;
    const int w    = tid >> 6;        // wave id == head id
    const int nl   = lane & 15;
    const int q    = lane >> 4;
    const int arow = tid >> 2;          // staging: row 0..63
    const int acol = (tid & 3) * 8;     // col-group within each 32-chunk

    const uint4* bW = w1f + (long)w * (8 * 4 * 64) + lane;

    // per-wave constants for the epilogue
    float b1v[4], w2v[4];
    #pragma unroll
    for (int nb = 0; nb < 4; ++nb) {
        int d = nb * 16 + nl;
        b1v[nb] = b1[w * HD_ + d];
        w2v[nb] = w2[w * HD_ + d];
    }

    // ---- prologue: stage tile 0 (exposed once per block) ----
    {
        const int rb0 = (blockIdx.x * NT_) * TILE_;
        const float* aptr = x + (long)(rb0 + arow) * C_ + acol;
        #pragma unroll
        for (int kc = 0; kc < 8; ++kc) {
            const float4* ap = (const float4*)(aptr + kc * 32);
            float4 f0 = ap[0], f1 = ap[1];
            uint4 ua;
            ua.x = pack_bf16x2(f0.x, f0.y); ua.y = pack_bf16x2(f0.z, f0.w);
            ua.z = pack_bf16x2(f1.x, f1.y); ua.w = pack_bf16x2(f1.z, f1.w);
            *(uint4*)&shA[arow * ASTRIDE + kc * 32 + acol] = ua;
        }
    }
    uint4 bFa[4], bFb[4];
    #pragma unroll
    for (int nb = 0; nb < 4; ++nb) bFa[nb] = bW[nb * 64];
    __syncthreads();

    #pragma unroll 1
    for (int it = 0; it < NT_; ++it) {
        const int tile    = blockIdx.x * NT_ + it;
        const int rowbase = tile * TILE_;
        const int b       = tile >> 6;
        const int tbase   = (tile & 63) * TILE_;
        const bool more   = (it + 1 < NT_);
        const float* aN   = x + (long)(rowbase + TILE_ + arow) * C_ + acol; // next tile

        // ---- K-loop: 8 steps x 16 MFMA, depth-1 B prefetch ----
        floatx4 acc[4][4];
        #pragma unroll
        for (int i = 0; i < 4; ++i)
            #pragma unroll
            for (int j = 0; j < 4; ++j)
                acc[i][j] = (floatx4){0.f, 0.f, 0.f, 0.f};
        #pragma unroll
        for (int kp = 0; kp < 4; ++kp) {
            const int ks0 = 2 * kp, ks1 = 2 * kp + 1;
            #pragma unroll
            for (int nb = 0; nb < 4; ++nb) bFb[nb] = bW[(ks1 * 4 + nb) * 64];
            #pragma unroll
            for (int mb = 0; mb < 4; ++mb) {
                short8 a = *(const short8*)&shA[(mb * 16 + nl) * ASTRIDE + ks0 * 32 + q * 8];
                #pragma unroll
                for (int nb = 0; nb < 4; ++nb)
                    acc[mb][nb] = __builtin_amdgcn_mfma_f32_16x16x32_bf16(
                        a, __builtin_bit_cast(short8, bFa[nb]), acc[mb][nb], 0, 0, 0);
            }
            if (kp < 3) {
                #pragma unroll
                for (int nb = 0; nb < 4; ++nb) bFa[nb] = bW[((ks0 + 2) * 4 + nb) * 64];
            }
            #pragma unroll
            for (int mb = 0; mb < 4; ++mb) {
                short8 a = *(const short8*)&shA[(mb * 16 + nl) * ASTRIDE + ks1 * 32 + q * 8];
                #pragma unroll
                for (int nb = 0; nb < 4; ++nb)
                    acc[mb][nb] = __builtin_amdgcn_mfma_f32_16x16x32_bf16(
                        a, __builtin_bit_cast(short8, bFb[nb]), acc[mb][nb], 0, 0, 0);
            }
        }
        // restore ks=0 fragments for the next tile's K-loop (same data every tile)
        #pragma unroll
        for (int nb = 0; nb < 4; ++nb) bFa[nb] = bW[nb * 64];

        // ---- issue stage half-1 for next tile (latency hides under epilogue) ----
        float4 f0h[4], f1h[4];
        if (more) {
            #pragma unroll
            for (int kc = 0; kc < 4; ++kc) {
                const float4* ap = (const float4*)(aN + kc * 32);
                f0h[kc] = ap[0]; f1h[kc] = ap[1];
            }
        }

        // ---- epilogue: s(t) = sum_d tanh(P + b1)*w2 ----
        #pragma unroll
        for (int mb = 0; mb < 4; ++mb) {
            float p[4];
            #pragma unroll
            for (int r = 0; r < 4; ++r) {
                float s = 0.f;
                #pragma unroll
                for (int nb = 0; nb < 4; ++nb)
                    s += fast_tanh(acc[mb][nb][r] + b1v[nb]) * w2v[nb];
                p[r] = s;
            }
            #pragma unroll
            for (int m = 1; m < 16; m <<= 1)
                #pragma unroll
                for (int r = 0; r < 4; ++r)
                    p[r] += __shfl_xor(p[r], m, 64);
            if (nl == 0) {
                #pragma unroll
                for (int r = 0; r < 4; ++r)
                    sS[w * TILE_ + mb * 16 + q * 4 + r] = p[r];
            }
        }

        // ---- pack half-1 (loads have had the whole epilogue to land) ----
        uint4 stA[4];
        if (more) {
            #pragma unroll
            for (int kc = 0; kc < 4; ++kc) {
                stA[kc].x = pack_bf16x2(f0h[kc].x, f0h[kc].y);
                stA[kc].y = pack_bf16x2(f0h[kc].z, f0h[kc].w);
                stA[kc].z = pack_bf16x2(f1h[kc].x, f1h[kc].y);
                stA[kc].w = pack_bf16x2(f1h[kc].z, f1h[kc].w);
            }
        }

        // ---- phase 2: per-head local softmax partials (reads own-wave sS) ----
        {
            float s = sS[w * TILE_ + lane];
            float m = s;
            #pragma unroll
            for (int off = 1; off < 64; off <<= 1)
                m = fmaxf(m, __shfl_xor(m, off, 64));
            float e = __expf(s - m);
            float Ss = e;
            #pragma unroll
            for (int off = 1; off < 64; off <<= 1)
                Ss += __shfl_xor(Ss, off, 64);
            sP4[lane * 4 + w] = e;
            rawscore[((long)(b * H_ + w)) * T_ + tbase + lane] = s;
            if (lane == 0) {
                mS[((long)tile * H_ + w) * 2 + 0] = m;
                mS[((long)tile * H_ + w) * 2 + 1] = Ss;
            }
        }

        // ---- issue stage half-2 (latency hides under barrier + phase 3) ----
        float4 f0g[4], f1g[4];
        if (more) {
            #pragma unroll
            for (int kc = 0; kc < 4; ++kc) {
                const float4* ap = (const float4*)(aN + (kc + 4) * 32);
                f0g[kc] = ap[0]; f1g[kc] = ap[1];
            }
        }

        __syncthreads();   // all waves past their K-loop ds_reads; sP4 visible

        // ---- write half-1 into shA (next tile) ----
        if (more) {
            #pragma unroll
            for (int kc = 0; kc < 4; ++kc)
                *(uint4*)&shA[arow * ASTRIDE + kc * 32 + acol] = stA[kc];
        }

        // ---- phase 3: partial contexts (x re-read for CURRENT tile, L2-hot) ----
        {
            float c0 = 0.f, c1 = 0.f, c2 = 0.f, c3 = 0.f;
            const float* xr = x + (long)rowbase * C_ + tid;
            const float4* pv4 = (const float4*)sP4;
            #pragma unroll 8
            for (int t = 0; t < TILE_; ++t) {
                float xv = xr[(long)t * C_];
                float4 pv = pv4[t];
                c0 += pv.x * xv;
                c1 += pv.y * xv;
                c2 += pv.z * xv;
                c3 += pv.w * xv;
            }
            float* o = ctxp + (long)tile * (H_ * C_) + tid;
            o[0]   = c0;
            o[256] = c1;
            o[512] = c2;
            o[768] = c3;
        }

        // ---- pack + write half-2 ----
        if (more) {
            #pragma unroll
            for (int kc = 0; kc < 4; ++kc) {
                uint4 ub;
                ub.x = pack_bf16x2(f0g[kc].x, f0g[kc].y);
                ub.y = pack_bf16x2(f0g[kc].z, f0g[kc].w);
                ub.z = pack_bf16x2(f1g[kc].x, f1g[kc].y);
                ub.w = pack_bf16x2(f1g[kc].z, f1g[kc].w);
                *(uint4*)&shA[arow * ASTRIDE + (kc + 4) * 32 + acol] = ub;
            }
            __syncthreads();   // shA fully staged before next K-loop
        }
    }
}

// ---------------- K2: combine partials -> multi + per-(b,h) {m, invS} ----------------
__global__ __launch_bounds__(1024)
void k2_combine(const float* __restrict__ ctxp, const float* __restrict__ mS,
                float* __restrict__ gms, float* __restrict__ multi) {
    __shared__ float sm[NBLK_], sSl[NBLK_];
    __shared__ float red[4][256];
    int bh = blockIdx.x;              // b*H + h
    int b = bh >> 2, h = bh & 3;
    int tid = threadIdx.x;
    int c  = tid & 255;
    int js = tid >> 8;                // 0..3
    if (tid < NBLK_) {
        long blk = (long)b * NBLK_ + tid;
        sm[tid]  = mS[(blk * H_ + h) * 2 + 0];
        sSl[tid] = mS[(blk * H_ + h) * 2 + 1];
    }
    __syncthreads();
    float m = -INFINITY;
    #pragma unroll 8
    for (int j = 0; j < NBLK_; ++j) m = fmaxf(m, sm[j]);
    float S = 0.f;
    #pragma unroll 8
    for (int j = 0; j < NBLK_; ++j) S += sSl[j] * __expf(sm[j] - m);
    float invS = 1.0f / S;
    if (tid == 0) { gms[bh * 2 + 0] = m; gms[bh * 2 + 1] = invS; }

    float acc = 0.f;
    #pragma unroll
    for (int jj = 0; jj < NBLK_ / 4; ++jj) {
        int j = js * (NBLK_ / 4) + jj;
        acc += ctxp[((long)(b * NBLK_ + j) * H_ + h) * C_ + c] * __expf(sm[j] - m);
    }
    red[js][c] = acc;
    __syncthreads();
    if (js == 0)
        multi[(long)b * (H_ * C_) + h * C_ + c] =
            (red[0][c] + red[1][c] + red[2][c] + red[3][c]) * invS;
}

// ---------------- K3: weights = exp(raw - m) * invS ----------------
__global__ void k3_weights(const float* __restrict__ gms, float* __restrict__ weights) {
    int bh = blockIdx.x >> 1, half = blockIdx.x & 1;
    float m = gms[bh * 2 + 0], invS = gms[bh * 2 + 1];
    float4* wr = (float4*)(weights + (long)bh * T_ + half * 2048);
    int tid = threadIdx.x;
    #pragma unroll
    for (int i = 0; i < 2; ++i) {
        float4 v = wr[tid + i * 256];
        v.x = __expf(v.x - m) * invS;
        v.y = __expf(v.y - m) * invS;
        v.z = __expf(v.z - m) * invS;
        v.w = __expf(v.w - m) * invS;
        wr[tid + i * 256] = v;
    }
}

// ---------------- K4a: out_raw = multi @ Wo^T + bo (wave-cooperative dots) ----------------
__global__ __launch_bounds__(256)
void k4a_proj(const float* __restrict__ multiG, const float* __restrict__ Wo,
              const float* __restrict__ bo, float* __restrict__ outraw) {
    __shared__ __align__(16) float multi[1024];
    int b = blockIdx.x >> 4, cs = blockIdx.x & 15;
    int tid = threadIdx.x, w = tid >> 6, l = tid & 63;
    ((float4*)multi)[tid] = ((const float4*)(multiG + (long)b * 1024))[tid];
    __syncthreads();
    float a[4];
    #pragma unroll
    for (int cc = 0; cc < 4; ++cc) {
        int c = cs * 16 + w * 4 + cc;
        const float4* wrow = (const float4*)(Wo + (long)c * 1024);
        const float4* mv = (const float4*)multi;
        float s = 0.f;
        #pragma unroll
        for (int k = 0; k < 4; ++k) {
            float4 wv = wrow[k * 64 + l];
            float4 m4 = mv[k * 64 + l];
            s += wv.x * m4.x + wv.y * m4.y + wv.z * m4.z + wv.w * m4.w;
        }
        a[cc] = s;
    }
    #pragma unroll
    for (int off = 1; off < 64; off <<= 1)
        #pragma unroll
        for (int cc = 0; cc < 4; ++cc)
            a[cc] += __shfl_xor(a[cc], off, 64);
    if (l == 0) {
        #pragma unroll
        for (int cc = 0; cc < 4; ++cc) {
            int c = cs * 16 + w * 4 + cc;
            outraw[(long)b * C_ + c] = a[cc] + bo[c];
        }
    }
}

// ---------------- K4b: LayerNorm over the 256 outputs per batch row ----------------
__global__ void k4b_ln(const float* __restrict__ outraw, const float* __restrict__ gamma,
                       const float* __restrict__ beta, float* __restrict__ out) {
    __shared__ float red[256];
    int b = blockIdx.x, tid = threadIdx.x;
    float acc = outraw[(long)b * C_ + tid];
    red[tid] = acc; __syncthreads();
    for (int st = 128; st > 0; st >>= 1) {
        if (tid < st) red[tid] += red[tid + st];
        __syncthreads();
    }
    float mu = red[0] * (1.0f / 256.0f); __syncthreads();
    float dv = acc - mu;
    red[tid] = dv * dv; __syncthreads();
    for (int st = 128; st > 0; st >>= 1) {
        if (tid < st) red[tid] += red[tid + st];
        __syncthreads();
    }
    float var = red[0] * (1.0f / 256.0f);
    out[(long)b * C_ + tid] = dv * rsqrtf(var + EPS_) * gamma[tid] + beta[tid];
}

extern "C" void kernel_launch(void* const* d_in, const int* in_sizes, int n_in,
                              void* d_out, int out_size, void* d_ws, size_t ws_size,
                              hipStream_t stream) {
    const float* x     = (const float*)d_in[0];
    const float* W1    = (const float*)d_in[1];
    const float* b1    = (const float*)d_in[2];
    const float* w2    = (const float*)d_in[3];
    const float* Wo    = (const float*)d_in[4];
    const float* bo    = (const float*)d_in[5];
    const float* gamma = (const float*)d_in[6];
    const float* beta  = (const float*)d_in[7];

    float* out     = (float*)d_out;          // (B,C) = 16384 floats
    float* weights = out + B_ * C_;          // (B,H,T) = 1048576 floats (raw scores first)

    // workspace layout
    const long NB = (long)B_ * NBLK_;        // 4096 tiles
    float* ctxp   = (float*)d_ws;            // 4096*1024 = 16 MiB
    float* mS     = ctxp + NB * (H_ * C_);   // 4096*4*2
    float* multi  = mS + NB * H_ * 2;        // 64*1024
    uint4* w1f    = (uint4*)(multi + B_ * H_ * C_);   // 128 KiB
    float* gms    = (float*)w1f + 32768;     // 256*2
    float* outraw = gms + 512;               // 64*256

    k0_w1frag <<<32, 256, 0, stream>>>(W1, w1f);
    k1_fused  <<<GRID1_, 256, 0, stream>>>(x, w1f, b1, w2, weights, ctxp, mS);
    k2_combine<<<256, 1024, 0, stream>>>(ctxp, mS, gms, multi);
    k3_weights<<<512, 256, 0, stream>>>(gms, weights);
    k4a_proj  <<<1024, 256, 0, stream>>>(multi, Wo, bo, outraw);
    k4b_ln    <<<64, 256, 0, stream>>>(outraw, gamma, beta, out);
}

// Round 8
// 433.663 us; speedup vs baseline: 1.6937x; 1.6937x over previous
//
#include <hip/hip_runtime.h>
#include <hip/hip_bf16.h>
#include <math.h>

#define B_ 64
#define T_ 4096
#define C_ 256
#define H_ 4
#define HD_ 64
#define EPS_ 1e-5f

#define TILE_ 64
#define NBLK_ 64    // T_/TILE_

typedef __attribute__((ext_vector_type(4))) float floatx4;
typedef __attribute__((ext_vector_type(8))) short short8;   // 8 bf16 = 4 VGPRs (MFMA A/B frag)

#if __has_builtin(__builtin_amdgcn_cvt_pk_bf16_f32)
typedef __attribute__((ext_vector_type(2))) __bf16 bf16x2_t;
__device__ __forceinline__ unsigned int pack_bf16x2(float a, float b) {
    bf16x2_t v = __builtin_amdgcn_cvt_pk_bf16_f32(a, b);
    return __builtin_bit_cast(unsigned int, v);
}
#else
__device__ __forceinline__ unsigned int pack_bf16x2(float a, float b) {
    unsigned int ua = __builtin_bit_cast(unsigned int, a);
    unsigned int ub = __builtin_bit_cast(unsigned int, b);
    ua = (ua + 0x7fffu + ((ua >> 16) & 1u)) >> 16;   // RNE
    ub = (ub + 0x7fffu + ((ub >> 16) & 1u)) >> 16;
    return ua | (ub << 16);
}
#endif

// tanh(x) = 1 - 2/(e^{2x}+1) = 1 - 2*rcp(exp2(x*2log2e)+1); ~5 ops, err ~1e-7.
__device__ __forceinline__ float fast_tanh(float v) {
    float t = v * 2.8853900817779268f;          // 2*log2(e)
#if __has_builtin(__builtin_amdgcn_exp2f)
    float e2 = __builtin_amdgcn_exp2f(t);
#else
    float e2 = exp2f(t);
#endif
#if __has_builtin(__builtin_amdgcn_rcpf)
    return fmaf(-2.0f, __builtin_amdgcn_rcpf(e2 + 1.0f), 1.0f);
#else
    return 1.0f - 2.0f / (e2 + 1.0f);
#endif
}

// ---------------- K0: W1 (H,C,HD) fp32 -> fragment-major bf16 B-operand ----------------
// w1f[((h*8 + ks)*4 + nb)*64 + lane] = uint4 holding 8 bf16:
//   B[nb*16 + nl][ks*32 + q*8 + j], j=0..7   (nl = lane&15, q = lane>>4)
__global__ void k0_w1frag(const float* __restrict__ W1, uint4* __restrict__ w1f) {
    int h  = blockIdx.x >> 3;       // grid 32 = H*8
    int ks = blockIdx.x & 7;
    int nb = threadIdx.x >> 6;      // 4 waves = 4 n-tiles
    int l  = threadIdx.x & 63;
    int nl = l & 15, q = l >> 4;
    int d  = nb * 16 + nl;
    const float* src = W1 + ((long)h * C_ + ks * 32 + q * 8) * HD_ + d;
    float v[8];
    #pragma unroll
    for (int j = 0; j < 8; ++j) v[j] = src[j * HD_];
    uint4 ua;
    ua.x = pack_bf16x2(v[0], v[1]); ua.y = pack_bf16x2(v[2], v[3]);
    ua.z = pack_bf16x2(v[4], v[5]); ua.w = pack_bf16x2(v[6], v[7]);
    w1f[((long)blockIdx.x * 4 + nb) * 64 + l] = ua;
}

// ---------------- K1 fused (R2/R6 proven structure): scores + partial softmax + ctx ----------------
// grid 4096 (64 rows each), block 256 = 4 waves, wave w = head w.
#define ASTRIDE 264   // bf16 elements per row (256 + 8 pad)
__global__ __launch_bounds__(256, 4)
void k1_fused(const float* __restrict__ x, const uint4* __restrict__ w1f,
              const float* __restrict__ b1, const float* __restrict__ w2,
              float* __restrict__ rawscore, float* __restrict__ ctxp,
              float* __restrict__ mS) {
    __shared__ __align__(16) unsigned short shA[TILE_ * ASTRIDE];  // 33 KiB
    __shared__ float sS[4 * TILE_];
    __shared__ __align__(16) float sP4[TILE_ * 4];

    const int tid  = threadIdx.x;
    const int lane = tid & 63;
    const int w    = tid >> 6;        // wave id == head id
    const int nl   = lane & 15;
    const int q    = lane >> 4;
    const int rowbase = blockIdx.x * TILE_;
    const int b       = blockIdx.x >> 6;
    const int tbase   = (blockIdx.x & 63) * TILE_;

    // ---- stage full A tile ----
    const int arow = tid >> 2;          // 0..63
    const int acol = (tid & 3) * 8;     // 0,8,16,24 within each 32-chunk
    const float* aptr = x + (long)(rowbase + arow) * C_ + acol;
    #pragma unroll
    for (int kc = 0; kc < 8; ++kc) {
        const float4* ap = (const float4*)(aptr + kc * 32);
        float4 f0 = ap[0], f1 = ap[1];
        uint4 ua;
        ua.x = pack_bf16x2(f0.x, f0.y); ua.y = pack_bf16x2(f0.z, f0.w);
        ua.z = pack_bf16x2(f1.x, f1.y); ua.w = pack_bf16x2(f1.z, f1.w);
        *(uint4*)&shA[arow * ASTRIDE + kc * 32 + acol] = ua;
    }

    floatx4 acc[4][4];
    #pragma unroll
    for (int i = 0; i < 4; ++i)
        #pragma unroll
        for (int j = 0; j < 4; ++j)
            acc[i][j] = (floatx4){0.f, 0.f, 0.f, 0.f};

    const uint4* bW = w1f + (long)w * (8 * 4 * 64) + lane;

    uint4 bFa[4], bFb[4];
    #pragma unroll
    for (int nb = 0; nb < 4; ++nb) bFa[nb] = bW[nb * 64];

    __syncthreads();   // the ONLY K-side barrier

    #pragma unroll
    for (int kp = 0; kp < 4; ++kp) {
        const int ks0 = 2 * kp, ks1 = 2 * kp + 1;
        #pragma unroll
        for (int nb = 0; nb < 4; ++nb) bFb[nb] = bW[(ks1 * 4 + nb) * 64];
        #pragma unroll
        for (int mb = 0; mb < 4; ++mb) {
            short8 a = *(const short8*)&shA[(mb * 16 + nl) * ASTRIDE + ks0 * 32 + q * 8];
            #pragma unroll
            for (int nb = 0; nb < 4; ++nb)
                acc[mb][nb] = __builtin_amdgcn_mfma_f32_16x16x32_bf16(
                    a, __builtin_bit_cast(short8, bFa[nb]), acc[mb][nb], 0, 0, 0);
        }
        if (kp < 3) {
            #pragma unroll
            for (int nb = 0; nb < 4; ++nb) bFa[nb] = bW[((ks0 + 2) * 4 + nb) * 64];
        }
        #pragma unroll
        for (int mb = 0; mb < 4; ++mb) {
            short8 a = *(const short8*)&shA[(mb * 16 + nl) * ASTRIDE + ks1 * 32 + q * 8];
            #pragma unroll
            for (int nb = 0; nb < 4; ++nb)
                acc[mb][nb] = __builtin_amdgcn_mfma_f32_16x16x32_bf16(
                    a, __builtin_bit_cast(short8, bFb[nb]), acc[mb][nb], 0, 0, 0);
        }
    }

    // ---- epilogue: s(t) = sum_d tanh(P + b1)*w2 ----
    float b1v[4], w2v[4];
    #pragma unroll
    for (int nb = 0; nb < 4; ++nb) {
        int d = nb * 16 + nl;
        b1v[nb] = b1[w * HD_ + d];
        w2v[nb] = w2[w * HD_ + d];
    }
    #pragma unroll
    for (int mb = 0; mb < 4; ++mb) {
        float p[4];
        #pragma unroll
        for (int r = 0; r < 4; ++r) {
            float s = 0.f;
            #pragma unroll
            for (int nb = 0; nb < 4; ++nb)
                s += fast_tanh(acc[mb][nb][r] + b1v[nb]) * w2v[nb];
            p[r] = s;
        }
        #pragma unroll
        for (int m = 1; m < 16; m <<= 1)
            #pragma unroll
            for (int r = 0; r < 4; ++r)
                p[r] += __shfl_xor(p[r], m, 64);
        if (nl == 0) {
            #pragma unroll
            for (int r = 0; r < 4; ++r)
                sS[w * TILE_ + mb * 16 + q * 4 + r] = p[r];
        }
    }

    // ---- phase 2: per-head local softmax partials over 64 t ----
    {
        float s = sS[w * TILE_ + lane];
        float m = s;
        #pragma unroll
        for (int off = 1; off < 64; off <<= 1)
            m = fmaxf(m, __shfl_xor(m, off, 64));
        float e = __expf(s - m);
        float Ss = e;
        #pragma unroll
        for (int off = 1; off < 64; off <<= 1)
            Ss += __shfl_xor(Ss, off, 64);
        sP4[lane * 4 + w] = e;
        rawscore[((long)(b * H_ + w)) * T_ + tbase + lane] = s;
        if (lane == 0) {
            mS[((long)blockIdx.x * H_ + w) * 2 + 0] = m;
            mS[((long)blockIdx.x * H_ + w) * 2 + 1] = Ss;
        }
    }
    __syncthreads();

    // ---- phase 3: partial contexts (x re-read, cache-hot) ----
    {
        float c0 = 0.f, c1 = 0.f, c2 = 0.f, c3 = 0.f;
        const float* xr = x + (long)rowbase * C_ + tid;
        const float4* pv4 = (const float4*)sP4;
        #pragma unroll 8
        for (int t = 0; t < TILE_; ++t) {
            float xv = xr[(long)t * C_];
            float4 pv = pv4[t];
            c0 += pv.x * xv;
            c1 += pv.y * xv;
            c2 += pv.z * xv;
            c3 += pv.w * xv;
        }
        float* o = ctxp + (long)blockIdx.x * (H_ * C_) + tid;
        o[0]   = c0;
        o[256] = c1;
        o[512] = c2;
        o[768] = c3;
    }
}

// ---------------- K2: combine partials -> multi, rewrite weights in place ----------------
// grid 256 = (b,h); 1024 threads. Folds the old K3: each thread rewrites one
// float4 of this (b,h)'s weights row (4096 floats / 1024 threads).
__global__ __launch_bounds__(1024)
void k2_combine(const float* __restrict__ ctxp, const float* __restrict__ mS,
                float* __restrict__ weights, float* __restrict__ multi) {
    __shared__ float sm[NBLK_], sSl[NBLK_];
    __shared__ float red[4][256];
    int bh = blockIdx.x;              // b*H + h
    int b = bh >> 2, h = bh & 3;
    int tid = threadIdx.x;
    int c  = tid & 255;
    int js = tid >> 8;                // 0..3
    if (tid < NBLK_) {
        long blk = (long)b * NBLK_ + tid;
        sm[tid]  = mS[(blk * H_ + h) * 2 + 0];
        sSl[tid] = mS[(blk * H_ + h) * 2 + 1];
    }
    __syncthreads();
    float m = -INFINITY;
    #pragma unroll 8
    for (int j = 0; j < NBLK_; ++j) m = fmaxf(m, sm[j]);
    float S = 0.f;
    #pragma unroll 8
    for (int j = 0; j < NBLK_; ++j) S += sSl[j] * __expf(sm[j] - m);
    float invS = 1.0f / S;

    // ---- folded K3: weights row rewrite (raw scores -> softmax weights) ----
    {
        float4* wr = (float4*)(weights + (long)bh * T_);
        float4 v = wr[tid];
        v.x = __expf(v.x - m) * invS;
        v.y = __expf(v.y - m) * invS;
        v.z = __expf(v.z - m) * invS;
        v.w = __expf(v.w - m) * invS;
        wr[tid] = v;
    }

    // ---- ctx combine (4-way j-split + LDS reduce) ----
    float acc = 0.f;
    #pragma unroll
    for (int jj = 0; jj < NBLK_ / 4; ++jj) {
        int j = js * (NBLK_ / 4) + jj;
        acc += ctxp[((long)(b * NBLK_ + j) * H_ + h) * C_ + c] * __expf(sm[j] - m);
    }
    red[js][c] = acc;
    __syncthreads();
    if (js == 0)
        multi[(long)b * (H_ * C_) + h * C_ + c] =
            (red[0][c] + red[1][c] + red[2][c] + red[3][c]) * invS;
}

// ---------------- K4: fused projection + bias + LayerNorm ----------------
// grid 64 (one block per batch row), 1024 threads = 16 waves.
// Wave w computes outputs c = w*16 + cc (cc 0..15) via lane-parallel coalesced
// dots + shuffle reduce; then in-block LayerNorm over the 256 outputs.
__global__ __launch_bounds__(1024)
void k4_fused(const float* __restrict__ multiG, const float* __restrict__ Wo,
              const float* __restrict__ bo, const float* __restrict__ gamma,
              const float* __restrict__ beta, float* __restrict__ out) {
    __shared__ float sOut[256];
    __shared__ float red[256];
    int b = blockIdx.x, tid = threadIdx.x, w = tid >> 6, l = tid & 63;

    // lane-resident multi fragment: lane l holds j = k*256 + l*4 .. +3 (k=0..3)
    float4 mreg[4];
    const float4* mv = (const float4*)(multiG + (long)b * 1024);
    #pragma unroll
    for (int k = 0; k < 4; ++k) mreg[k] = mv[k * 64 + l];

    #pragma unroll
    for (int cc = 0; cc < 16; ++cc) {
        int c = w * 16 + cc;
        const float4* wrow = (const float4*)(Wo + (long)c * 1024);
        float s = 0.f;
        #pragma unroll
        for (int k = 0; k < 4; ++k) {
            float4 wv = wrow[k * 64 + l];
            s += wv.x * mreg[k].x + wv.y * mreg[k].y + wv.z * mreg[k].z + wv.w * mreg[k].w;
        }
        #pragma unroll
        for (int off = 1; off < 64; off <<= 1)
            s += __shfl_xor(s, off, 64);
        if (l == 0) sOut[c] = s + bo[c];
    }
    __syncthreads();

    // ---- LayerNorm (threads 0..255 carry data; all threads hit barriers) ----
    float acc = 0.f;
    if (tid < 256) { acc = sOut[tid]; red[tid] = acc; }
    __syncthreads();
    for (int st = 128; st > 0; st >>= 1) {
        if (tid < st) red[tid] += red[tid + st];
        __syncthreads();
    }
    float mu = red[0] * (1.0f / 256.0f);
    __syncthreads();
    float dv = acc - mu;
    if (tid < 256) red[tid] = dv * dv;
    __syncthreads();
    for (int st = 128; st > 0; st >>= 1) {
        if (tid < st) red[tid] += red[tid + st];
        __syncthreads();
    }
    float var = red[0] * (1.0f / 256.0f);
    if (tid < 256)
        out[(long)b * C_ + tid] = dv * rsqrtf(var + EPS_) * gamma[tid] + beta[tid];
}

extern "C" void kernel_launch(void* const* d_in, const int* in_sizes, int n_in,
                              void* d_out, int out_size, void* d_ws, size_t ws_size,
                              hipStream_t stream) {
    const float* x     = (const float*)d_in[0];
    const float* W1    = (const float*)d_in[1];
    const float* b1    = (const float*)d_in[2];
    const float* w2    = (const float*)d_in[3];
    const float* Wo    = (const float*)d_in[4];
    const float* bo    = (const float*)d_in[5];
    const float* gamma = (const float*)d_in[6];
    const float* beta  = (const float*)d_in[7];

    float* out     = (float*)d_out;          // (B,C) = 16384 floats
    float* weights = out + B_ * C_;          // (B,H,T) = 1048576 floats (raw scores first)

    // workspace layout
    const long NB = (long)B_ * NBLK_;        // 4096 k1 tiles
    float* ctxp   = (float*)d_ws;            // 4096*1024 = 16 MiB
    float* mS     = ctxp + NB * (H_ * C_);   // 4096*4*2
    float* multi  = mS + NB * H_ * 2;        // 64*1024
    uint4* w1f    = (uint4*)(multi + B_ * H_ * C_);   // 128 KiB

    k0_w1frag <<<32, 256, 0, stream>>>(W1, w1f);
    k1_fused  <<<NB, 256, 0, stream>>>(x, w1f, b1, w2, weights, ctxp, mS);
    k2_combine<<<256, 1024, 0, stream>>>(ctxp, mS, weights, multi);
    k4_fused  <<<64, 1024, 0, stream>>>(multi, Wo, bo, gamma, beta, out);
}